// Round 4
// baseline (194.465 us; speedup 1.0000x reference)
//
#include <hip/hip_runtime.h>
#include <hip/hip_bf16.h>

// KANLayer: out = x @ Wb^T + silu(x) @ sum_g(Ws)^T
// One packed bf16 GEMM, K=2048: A'=[x|silu(x)], W'=[Wb|sum_g Ws], out=A'@W'^T.
// R12: split-K=2 -> m201 geometry. At full occupancy the wave tile is forced
//      to 64x64 (A x2 + B x4 LDS redundancy -> LDS-pipe floor ~21-28us; R9/R11
//      measured 37-41us regardless of barrier structure). Split K in half:
//      grid 256 = 32mt x 4nt x 2ks, block 512thr = 8 waves of 128x64
//      (BM=BN=256) -> 43.7 FLOP/LDS-byte (1.33x), m201's verified regime.
//      - 4-slot 32KB LDS ring (128KB), stage-ahead-3, vmcnt(8) counted (T4).
//      - per K=32 sub-step: 2 phases x 16 MFMA, B-frags reused across phases
//        (12 ds_read : 32 MFMA). barrier/lgkm0/setprio per phase (T3/T5).
//      - row-major [256][4-chunk] slots, chunk ^= row&3 both sides (T2):
//        bank-uniform b128 reads, 64B-segment coalesced gload_lds sources.
//      - C zeroed in prep; both ks halves unsafeAtomicAdd (HW f32 atomic);
//        ks pairs share an XCD (flat, flat+128 = same L2) for the 2nd RMW.

#define BATCH 8192
#define IN_F 1024
#define OUT_F 1024
#define KP 2048

typedef unsigned short ushort_t;
typedef __attribute__((ext_vector_type(8))) short short8;
typedef __attribute__((ext_vector_type(4))) float f32x4;

__device__ __forceinline__ ushort_t f2bf(float f) {
  union { float f; unsigned int u; } v;
  v.f = f;
  unsigned int u = v.u;
  u += 0x7fffu + ((u >> 16) & 1u);  // RNE
  return (ushort_t)(u >> 16);
}

// ---------------- merged prep (+ C zero for atomic accumulate) -----------
#define PREP_A_BLOCKS 4096
#define PREP_S_BLOCKS 1024
#define PREP_B_BLOCKS 1024
#define PREP_C_BLOCKS 2048
#define PREP_BLOCKS (PREP_A_BLOCKS + PREP_S_BLOCKS + PREP_B_BLOCKS + PREP_C_BLOCKS)

__global__ __launch_bounds__(256) void prep_all(
    const float* __restrict__ x, const float* __restrict__ Wb,
    const float* __restrict__ Ws, ushort_t* __restrict__ Apack,
    ushort_t* __restrict__ Wpack, float* __restrict__ Czero) {
  const int blk = blockIdx.x;
  const int t = threadIdx.x;

  if (blk < PREP_A_BLOCKS) {
    const int idx = blk * 256 + t;
    const int b = idx >> 7;
    const int i = (idx & 127) << 3;
    const float4 x0 = *(const float4*)(x + ((size_t)b << 10) + i);
    const float4 x1 = *(const float4*)(x + ((size_t)b << 10) + i + 4);
    float xv[8] = {x0.x, x0.y, x0.z, x0.w, x1.x, x1.y, x1.z, x1.w};
    ushort_t vb[8], vs[8];
#pragma unroll
    for (int j = 0; j < 8; ++j) {
      vb[j] = f2bf(xv[j]);
      vs[j] = f2bf(xv[j] / (1.0f + __expf(-xv[j])));
    }
    ushort_t* row = Apack + ((size_t)b << 11);
    *(short8*)(row + i) = *(short8*)vb;
    *(short8*)(row + IN_F + i) = *(short8*)vs;
  } else if (blk < PREP_A_BLOCKS + PREP_S_BLOCKS) {
    const int idx = (blk - PREP_A_BLOCKS) * 256 + t;
    const int o = idx >> 8;
    const int i0 = (idx & 255) << 2;
    ushort_t vs[4];
#pragma unroll
    for (int j = 0; j < 4; ++j) {
      const float4* p = (const float4*)(Ws + ((((size_t)o << 10) + i0 + j) << 3));
      const float4 a = p[0];
      const float4 b = p[1];
      vs[j] = f2bf(((a.x + a.y) + (a.z + a.w)) + ((b.x + b.y) + (b.z + b.w)));
    }
    *(ushort4*)(Wpack + ((size_t)o << 11) + IN_F + i0) = *(ushort4*)vs;
  } else if (blk < PREP_A_BLOCKS + PREP_S_BLOCKS + PREP_B_BLOCKS) {
    const int idx = (blk - PREP_A_BLOCKS - PREP_S_BLOCKS) * 256 + t;
    const int o = idx >> 8;
    const int c = (idx & 255) << 2;
    const float4 w = *(const float4*)(Wb + ((size_t)o << 10) + c);
    ushort4 v;
    v.x = f2bf(w.x); v.y = f2bf(w.y); v.z = f2bf(w.z); v.w = f2bf(w.w);
    *(ushort4*)(Wpack + ((size_t)o << 11) + c) = v;
  } else {
    const int idx = blk - (PREP_A_BLOCKS + PREP_S_BLOCKS + PREP_B_BLOCKS);
    float4* p = (float4*)Czero + (((size_t)(idx * 256 + t)) << 2);
    const float4 z = make_float4(0.f, 0.f, 0.f, 0.f);
    p[0] = z; p[1] = z; p[2] = z; p[3] = z;
  }
}

// ---------------- GEMM (split-K=2) ----------------
#define BM 256
#define BN 256
#define KHALF 1024
#define SUBK 32
#define NSUB (KHALF / SUBK)    // 32 sub-steps
#define SLOT_A 8192            // A region: 256 rows x 32 k = 16 KB (ushorts)
#define SLOT_US 16384          // + B region 16 KB -> 32 KB per slot
#define NSLOT 4                // 128 KB ring

typedef const __attribute__((address_space(1))) unsigned int gas_uint;
typedef __attribute__((address_space(3))) unsigned int las_uint;
#define ASYNC16(l, g) \
  __builtin_amdgcn_global_load_lds((gas_uint*)(g), (las_uint*)(l), 16, 0, 0)

#define LGKM0() do { \
  asm volatile("s_waitcnt lgkmcnt(0)" ::: "memory"); \
  __builtin_amdgcn_sched_barrier(0); \
} while (0)

__global__ __launch_bounds__(512, 2) void gemm_splitk(
    const ushort_t* __restrict__ A,  // [BATCH][KP]
    const ushort_t* __restrict__ W,  // [OUT_F][KP]
    float* __restrict__ C) {         // [BATCH][OUT_F], pre-zeroed
  __shared__ __align__(16) ushort_t lds[NSLOT * SLOT_US];  // 128 KB

  const int t = threadIdx.x;
  const int flat = blockIdx.x;           // 0..255
  const int ks = flat >> 7;              // K-half 0/1
  const int tile = flat & 127;
  const int loc = tile & 31;
  const int nt = tile >> 5;              // 0..3
  const int mt = (loc & 7) * 4 + (loc >> 3);  // 0..31; ks-pair same XCD (flat%8)

  const int lane = t & 63;
  const int wave = t >> 6;  // 0..7
  const int wr = wave >> 2; // 0..1 (M), wave tile 128x64
  const int wc = wave & 3;  // 0..3 (N)
  const int lr = lane & 15;
  const int lq = lane >> 4;

  // ---- staging: row = t>>2 (0..127), chunk = (t&3)^(row&3) (T2 source swz)
  // 4 threads/row cover the row's 64B k-segment (permuted inside) -> coalesced.
  const int srow = t >> 2;
  const int sc = (t & 3) ^ (srow & 3);
  const ushort_t* ga = A + (size_t)(mt * BM + srow) * KP + ks * KHALF + sc * 8;
  const ushort_t* gb = W + (size_t)(nt * BN + srow) * KP + ks * KHALF + sc * 8;
  const size_t rskip = (size_t)128 * KP;
  const int ldst = t * 8;  // linear 16B/thread inside each 8KB half-region

  // ---- fragment read offsets (read-side swz; bank-uniform: 8 touches/bank)
  int aoff[8], boff[4];
#pragma unroll
  for (int mi = 0; mi < 8; ++mi) {
    const int arow = wr * 128 + mi * 16 + lr;
    aoff[mi] = arow * 32 + ((lq ^ (arow & 3)) << 3);
  }
#pragma unroll
  for (int ni = 0; ni < 4; ++ni) {
    const int brow = wc * 64 + ni * 16 + lr;
    boff[ni] = brow * 32 + ((lq ^ (brow & 3)) << 3);
  }

  f32x4 acc[8][4];
#pragma unroll
  for (int mi = 0; mi < 8; ++mi)
#pragma unroll
    for (int ni = 0; ni < 4; ++ni) acc[mi][ni] = (f32x4){0.f, 0.f, 0.f, 0.f};

#define STAGE_A(slotoff, gka) do { \
    ASYNC16(lds + (slotoff) + ldst, (gka)); \
    ASYNC16(lds + (slotoff) + 4096 + ldst, (gka) + rskip); \
  } while (0)
#define STAGE_B(slotoff, gkb) do { \
    ASYNC16(lds + (slotoff) + SLOT_A + ldst, (gkb)); \
    ASYNC16(lds + (slotoff) + SLOT_A + 4096 + ldst, (gkb) + rskip); \
  } while (0)

#define MFMA16(MB)                                                           \
  do {                                                                       \
    __builtin_amdgcn_s_setprio(1);                                           \
    _Pragma("unroll") for (int mi = 0; mi < 4; ++mi)                         \
        _Pragma("unroll") for (int ni = 0; ni < 4; ++ni)                     \
            acc[(MB) + mi][ni] = __builtin_amdgcn_mfma_f32_16x16x32_bf16(    \
                af[mi], bf[ni], acc[(MB) + mi][ni], 0, 0, 0);                \
    __builtin_amdgcn_s_setprio(0);                                           \
  } while (0)

  // ---- prologue: slots 0,1,2 in flight; wait slot 0 (vmcnt: 12 out, keep 8)
  STAGE_A(0, ga);                    STAGE_B(0, gb);
  STAGE_A(SLOT_US, ga + SUBK);       STAGE_B(SLOT_US, gb + SUBK);
  STAGE_A(2 * SLOT_US, ga + 2 * SUBK); STAGE_B(2 * SLOT_US, gb + 2 * SUBK);
  asm volatile("s_waitcnt vmcnt(8)" ::: "memory");
  __builtin_amdgcn_s_barrier();
  __builtin_amdgcn_sched_barrier(0);

  // ---- main loop: 32 sub-steps; stage slot s+3; 2 phases x 16 MFMA ----
#pragma unroll 4
  for (int s = 0; s < NSUB; ++s) {
    const ushort_t* ab = lds + (s & 3) * SLOT_US;
    const ushort_t* bb = ab + SLOT_A;
    const int so = ((s + 3) & 3) * SLOT_US;
    const ushort_t* gpa = ga + (s + 3) * SUBK;
    const ushort_t* gpb = gb + (s + 3) * SUBK;
    short8 af[4], bf[4];

    // -- Phase A: A-frags 0..3 + all B-frags | stage next A half-tile --
#pragma unroll
    for (int i = 0; i < 4; ++i) af[i] = *(const short8*)(ab + aoff[i]);
#pragma unroll
    for (int i = 0; i < 4; ++i) bf[i] = *(const short8*)(bb + boff[i]);
    if (s < NSUB - 3) STAGE_A(so, gpa);
    __builtin_amdgcn_s_barrier();
    LGKM0();
    MFMA16(0);
    __builtin_amdgcn_s_barrier();

    // -- Phase B: A-frags 4..7 (B reused in regs) | stage next B half-tile --
#pragma unroll
    for (int i = 0; i < 4; ++i) af[i] = *(const short8*)(ab + aoff[4 + i]);
    if (s < NSUB - 3) STAGE_B(so, gpb);
    __builtin_amdgcn_s_barrier();
    LGKM0();
    MFMA16(4);
    // counted drain: slot s+1 must be resident; s+2,s+3 stay in flight.
    if (s < NSUB - 3) {
      asm volatile("s_waitcnt vmcnt(8)" ::: "memory");
    } else if (s == NSUB - 3) {
      asm volatile("s_waitcnt vmcnt(4)" ::: "memory");
    } else if (s == NSUB - 2) {
      asm volatile("s_waitcnt vmcnt(0)" ::: "memory");
    }
    __builtin_amdgcn_sched_barrier(0);
    if (s < NSUB - 1) {
      __builtin_amdgcn_s_barrier();
      __builtin_amdgcn_sched_barrier(0);
    }
  }

  // ---- epilogue: atomic accumulate (C pre-zeroed; 2 ks-halves add) ----
  // C/D layout: col = lane&15, row = (lane>>4)*4 + reg.
  const int col0 = nt * BN + wc * 64 + lr;
  const int row0 = mt * BM + wr * 128 + (lq << 2);
#pragma unroll
  for (int mi = 0; mi < 8; ++mi)
#pragma unroll
    for (int ni = 0; ni < 4; ++ni) {
      float* cp = C + (size_t)(row0 + mi * 16) * OUT_F + col0 + ni * 16;
#pragma unroll
      for (int rr = 0; rr < 4; ++rr)
        unsafeAtomicAdd(cp + (size_t)rr * OUT_F, acc[mi][ni][rr]);
    }
}

extern "C" void kernel_launch(void* const* d_in, const int* in_sizes, int n_in,
                              void* d_out, int out_size, void* d_ws, size_t ws_size,
                              hipStream_t stream) {
  const float* x = (const float*)d_in[0];
  const float* wb = (const float*)d_in[1];
  const float* ws = (const float*)d_in[2];
  float* out = (float*)d_out;

  ushort_t* Apack = (ushort_t*)d_ws;                                    // 33.5 MB
  ushort_t* Wpack = (ushort_t*)((char*)d_ws + (size_t)BATCH * KP * 2);  // +4 MB

  prep_all<<<PREP_BLOCKS, 256, 0, stream>>>(x, wb, ws, Apack, Wpack, out);
  gemm_splitk<<<dim3(256), dim3(512), 0, stream>>>(Apack, Wpack, out);
}

// Round 5
// 188.307 us; speedup vs baseline: 1.0327x; 1.0327x over previous
//
#include <hip/hip_runtime.h>
#include <hip/hip_bf16.h>

// KANLayer: out = x @ Wb^T + silu(x) @ sum_g(Ws)^T
// One packed bf16 GEMM, K=2048: A'=[x|silu(x)], W'=[Wb|sum_g Ws], out=A'@W'^T.
// R13: B off LDS (m169 "don't stage what cache-fits"). R12's split-K regressed
//      2x (confounded: 64B-row layout = irreducible 4-way bank conflict,
//      atomics, branchy loop) -> reverted to the R9-class geometry, ONE change:
//      Wpack is 4MB (L2-resident; 16KB/step/CU -> L1-resident). B-frags are
//      read straight from global (16 x 64B lines per wave-load, L1-served,
//      prefetched 1 step ahead into named double-buffered regs b0/b1).
//      Result: LDS pipe = A only (64KB rd + 32KB wr/step/CU ~ 870cyc),
//      VMEM/L1 pipe = B (~1000cyc), MFMA 1294cyc -> three independent pipes
//      vs R11's 176KB single-LDS-pipe sum-regime (~3300cyc/step).
//      One barrier/step (only the A-ring needs cross-wave sync); issue order
//      [B(s+1) x8][A-stage(s+2) x4] so vmcnt(4) at step end = A(s+1)+B(s+1)
//      landed, A(s+2) in flight (T4, in-order vmcnt). A staging + XOR swizzle
//      byte-identical to proven R9 (0 conflicts). T1 XCD map, T5 setprio kept.

#define BATCH 8192
#define IN_F 1024
#define OUT_F 1024
#define KP 2048

typedef unsigned short ushort_t;
typedef __attribute__((ext_vector_type(8))) short short8;
typedef __attribute__((ext_vector_type(4))) float f32x4;

__device__ __forceinline__ ushort_t f2bf(float f) {
  union { float f; unsigned int u; } v;
  v.f = f;
  unsigned int u = v.u;
  u += 0x7fffu + ((u >> 16) & 1u);  // RNE
  return (ushort_t)(u >> 16);
}

// ---------------- merged prep (unchanged: ~traffic floor) -----------
#define PREP_A_BLOCKS 4096
#define PREP_S_BLOCKS 1024
#define PREP_B_BLOCKS 1024
#define PREP_BLOCKS (PREP_A_BLOCKS + PREP_S_BLOCKS + PREP_B_BLOCKS)

__global__ __launch_bounds__(256) void prep_all(
    const float* __restrict__ x, const float* __restrict__ Wb,
    const float* __restrict__ Ws, ushort_t* __restrict__ Apack,
    ushort_t* __restrict__ Wpack) {
  const int blk = blockIdx.x;
  const int t = threadIdx.x;

  if (blk < PREP_A_BLOCKS) {
    const int idx = blk * 256 + t;
    const int b = idx >> 7;
    const int i = (idx & 127) << 3;
    const float4 x0 = *(const float4*)(x + ((size_t)b << 10) + i);
    const float4 x1 = *(const float4*)(x + ((size_t)b << 10) + i + 4);
    float xv[8] = {x0.x, x0.y, x0.z, x0.w, x1.x, x1.y, x1.z, x1.w};
    ushort_t vb[8], vs[8];
#pragma unroll
    for (int j = 0; j < 8; ++j) {
      vb[j] = f2bf(xv[j]);
      vs[j] = f2bf(xv[j] / (1.0f + __expf(-xv[j])));
    }
    ushort_t* row = Apack + ((size_t)b << 11);
    *(short8*)(row + i) = *(short8*)vb;
    *(short8*)(row + IN_F + i) = *(short8*)vs;
  } else if (blk < PREP_A_BLOCKS + PREP_S_BLOCKS) {
    const int idx = (blk - PREP_A_BLOCKS) * 256 + t;
    const int o = idx >> 8;
    const int i0 = (idx & 255) << 2;
    ushort_t vs[4];
#pragma unroll
    for (int j = 0; j < 4; ++j) {
      const float4* p = (const float4*)(Ws + ((((size_t)o << 10) + i0 + j) << 3));
      const float4 a = p[0];
      const float4 b = p[1];
      vs[j] = f2bf(((a.x + a.y) + (a.z + a.w)) + ((b.x + b.y) + (b.z + b.w)));
    }
    *(ushort4*)(Wpack + ((size_t)o << 11) + IN_F + i0) = *(ushort4*)vs;
  } else {
    const int idx = (blk - PREP_A_BLOCKS - PREP_S_BLOCKS) * 256 + t;
    const int o = idx >> 8;
    const int c = (idx & 255) << 2;
    const float4 w = *(const float4*)(Wb + ((size_t)o << 10) + c);
    ushort4 v;
    v.x = f2bf(w.x); v.y = f2bf(w.y); v.z = f2bf(w.z); v.w = f2bf(w.w);
    *(ushort4*)(Wpack + ((size_t)o << 11) + c) = v;
  }
}

// ---------------- GEMM ----------------
#define BM 256
#define BN 128
#define GBK 64
#define NSTEP (KP / GBK)       // 32
#define SLOT_US 16384          // A slot: 256 rows x 64 ushorts = 32 KB
#define NSLOT 3                // 96 KB A-ring

typedef const __attribute__((address_space(1))) unsigned int gas_uint;
typedef __attribute__((address_space(3))) unsigned int las_uint;
#define ASYNC16(l, g) \
  __builtin_amdgcn_global_load_lds((gas_uint*)(g), (las_uint*)(l), 16, 0, 0)

__global__ __launch_bounds__(512, 2) void gemm_packed(
    const ushort_t* __restrict__ A,  // [BATCH][KP]
    const ushort_t* __restrict__ W,  // [OUT_F][KP]
    float* __restrict__ C) {         // [BATCH][OUT_F]
  __shared__ __align__(16) ushort_t lds[NSLOT * SLOT_US];  // 96 KB, A only

  const int t = threadIdx.x;
  const int flat = blockIdx.x;           // 0..255
  const int xcd = flat & 7;
  const int local = flat >> 3;           // 0..31
  const int nt = local >> 2;             // 0..7
  const int mt = xcd * 4 + (local & 3);  // 0..31 (XCD-local A slabs)

  const int lane = t & 63;
  const int wave = t >> 6;  // 0..7
  const int wr = wave >> 1; // 0..3 (M)
  const int wc = wave & 1;  // 0..1 (N)
  const int lr = lane & 15;
  const int lq = lane >> 4;

  // ---- A staging (source-side swizzle; byte-identical to proven R9) ----
  // thread t -> LDS slot row = t>>3, phys chunk = t&7; fetched global
  // k-chunk = phys ^ (row&7) (stays in the row's 128B segment -> coalesced).
  const int srow = t >> 3;               // 0..63
  const int kc = (t & 7) ^ (srow & 7);   // swizzled source k-chunk
  const ushort_t* ga = A + (size_t)(mt * BM + srow) * KP + kc * 8;
  const int ldst = t * 8;                // ushort offset (t*16 B)
  const size_t rskip = (size_t)64 * KP;

  // ---- A fragment read offsets (read-side swizzle; proven, 0 conflicts) ----
  int aoff[2][4];
#pragma unroll
  for (int kk = 0; kk < 2; ++kk)
#pragma unroll
    for (int i = 0; i < 4; ++i) {
      const int arow = wr * 64 + i * 16 + lr;
      const int ks = kk * 4 + lq;
      aoff[kk][i] = arow * 64 + ((ks ^ (arow & 7)) << 3);
    }

  // ---- B fragment global pointers: frag j = (kk = j>>2, ni = j&3) ----
  // lane pattern: 16 rows (lr) x 64B contiguous (lq*16B) -> 16 full cache
  // lines per wave-load; Wpack is 4MB (L2-fits), 16KB/step/CU (L1-fits).
  const ushort_t* bp[8];
#pragma unroll
  for (int j = 0; j < 8; ++j) {
    const int ni = j & 3;
    const int kk = j >> 2;
    bp[j] = W + (size_t)(nt * BN + wc * 64 + ni * 16 + lr) * KP + kk * 32 + lq * 8;
  }

  f32x4 acc[4][4];
#pragma unroll
  for (int mi = 0; mi < 4; ++mi)
#pragma unroll
    for (int ni = 0; ni < 4; ++ni) acc[mi][ni] = (f32x4){0.f, 0.f, 0.f, 0.f};

  short8 b0[8], b1[8];
  int co = 0;              // compute ring offset (slot s%3)
  int so = 2 * SLOT_US;    // stage ring offset (slot (s+2)%3)
  const ushort_t* gsa = ga + 2 * GBK;  // A-stage source (tile s+2)
  int gk = GBK;            // B prefetch k-offset (tile s+1)

#define STAGE_A4()                                                            \
  do {                                                                        \
    ushort_t* sa = lds + so + ldst;                                           \
    ASYNC16(sa, gsa);                                                         \
    ASYNC16(sa + 4096, gsa + rskip);                                          \
    ASYNC16(sa + 8192, gsa + 2 * rskip);                                      \
    ASYNC16(sa + 12288, gsa + 3 * rskip);                                     \
    gsa += GBK;                                                               \
  } while (0)

// One K=64 step: compute from slot co with B-frags BC; prefetch B(s+1)->BN
// (issued BEFORE the A-stage so end-of-step vmcnt(4) covers it); stage A(s+2).
#define GEMM_STEP(BC, BN, DO_PREFETCH, DO_STAGE)                              \
  do {                                                                        \
    const ushort_t* ab = lds + co;                                            \
    short8 af[4];                                                             \
    _Pragma("unroll") for (int i = 0; i < 4; ++i)                             \
        af[i] = *(const short8*)(ab + aoff[0][i]);                            \
    if (DO_PREFETCH) {                                                        \
      _Pragma("unroll") for (int j = 0; j < 4; ++j)                           \
          BN[j] = *(const short8*)(bp[j] + gk);                               \
    }                                                                         \
    __builtin_amdgcn_sched_barrier(0);                                        \
    __builtin_amdgcn_s_setprio(1);                                            \
    _Pragma("unroll") for (int mi = 0; mi < 4; ++mi)                          \
        _Pragma("unroll") for (int ni = 0; ni < 4; ++ni)                      \
            acc[mi][ni] = __builtin_amdgcn_mfma_f32_16x16x32_bf16(            \
                af[mi], BC[ni], acc[mi][ni], 0, 0, 0);                        \
    __builtin_amdgcn_s_setprio(0);                                            \
    _Pragma("unroll") for (int i = 0; i < 4; ++i)                             \
        af[i] = *(const short8*)(ab + aoff[1][i]);                            \
    if (DO_PREFETCH) {                                                        \
      _Pragma("unroll") for (int j = 4; j < 8; ++j)                           \
          BN[j] = *(const short8*)(bp[j] + gk);                               \
      gk += GBK;                                                              \
    }                                                                         \
    if (DO_STAGE) STAGE_A4();                                                 \
    __builtin_amdgcn_sched_barrier(0);                                        \
    __builtin_amdgcn_s_setprio(1);                                            \
    _Pragma("unroll") for (int mi = 0; mi < 4; ++mi)                          \
        _Pragma("unroll") for (int ni = 0; ni < 4; ++ni)                      \
            acc[mi][ni] = __builtin_amdgcn_mfma_f32_16x16x32_bf16(            \
                af[mi], BC[4 + ni], acc[mi][ni], 0, 0, 0);                    \
    __builtin_amdgcn_s_setprio(0);                                            \
  } while (0)

#define ENDSTEP(VMC)                                                          \
  do {                                                                        \
    asm volatile("s_waitcnt vmcnt(" #VMC ")" ::: "memory");                   \
    __builtin_amdgcn_s_barrier();                                             \
    __builtin_amdgcn_sched_barrier(0);                                        \
    co += SLOT_US; if (co == NSLOT * SLOT_US) co = 0;                         \
    so += SLOT_US; if (so == NSLOT * SLOT_US) so = 0;                         \
  } while (0)

  // ---- prologue: order [A0 x4][B0 x8][A1 x4] -> vmcnt(4) = A0+B0 landed ----
  {
    ushort_t* sa0 = lds + ldst;
    ASYNC16(sa0, ga);
    ASYNC16(sa0 + 4096, ga + rskip);
    ASYNC16(sa0 + 8192, ga + 2 * rskip);
    ASYNC16(sa0 + 12288, ga + 3 * rskip);
#pragma unroll
    for (int j = 0; j < 8; ++j) b0[j] = *(const short8*)(bp[j]);
    ushort_t* sa1 = lds + SLOT_US + ldst;
    ASYNC16(sa1, ga + GBK);
    ASYNC16(sa1 + 4096, ga + GBK + rskip);
    ASYNC16(sa1 + 8192, ga + GBK + 2 * rskip);
    ASYNC16(sa1 + 12288, ga + GBK + 3 * rskip);
  }
  asm volatile("s_waitcnt vmcnt(4)" ::: "memory");
  __builtin_amdgcn_s_barrier();
  __builtin_amdgcn_sched_barrier(0);

  // ---- main loop: 30 steps as 15 double-steps (b0/b1 role swap) ----
#pragma unroll 1
  for (int s2 = 0; s2 < (NSTEP - 2) / 2; ++s2) {
    GEMM_STEP(b0, b1, true, true);
    ENDSTEP(4);
    GEMM_STEP(b1, b0, true, true);
    ENDSTEP(4);
  }
  // ---- tail: step 30 (prefetch B31, no stage), step 31 (pure compute) ----
  GEMM_STEP(b0, b1, true, false);
  ENDSTEP(0);
  GEMM_STEP(b1, b0, false, false);

  // ---- epilogue: C/D layout col=lane&15, row=(lane>>4)*4+reg ----
  const int col0 = nt * BN + wc * 64 + lr;
  const int row0 = mt * BM + wr * 64 + (lq << 2);
#pragma unroll
  for (int mi = 0; mi < 4; ++mi)
#pragma unroll
    for (int ni = 0; ni < 4; ++ni) {
      float* cp = C + (size_t)(row0 + mi * 16) * OUT_F + col0 + ni * 16;
#pragma unroll
      for (int rr = 0; rr < 4; ++rr) cp[(size_t)rr * OUT_F] = acc[mi][ni][rr];
    }
}

extern "C" void kernel_launch(void* const* d_in, const int* in_sizes, int n_in,
                              void* d_out, int out_size, void* d_ws, size_t ws_size,
                              hipStream_t stream) {
  const float* x = (const float*)d_in[0];
  const float* wb = (const float*)d_in[1];
  const float* ws = (const float*)d_in[2];
  float* out = (float*)d_out;

  ushort_t* Apack = (ushort_t*)d_ws;                                    // 33.5 MB
  ushort_t* Wpack = (ushort_t*)((char*)d_ws + (size_t)BATCH * KP * 2);  // +4 MB

  prep_all<<<PREP_BLOCKS, 256, 0, stream>>>(x, wb, ws, Apack, Wpack);
  gemm_packed<<<dim3((BATCH / BM) * (OUT_F / BN)), dim3(512), 0, stream>>>(Apack, Wpack, out);
}